// Round 3
// baseline (166.190 us; speedup 1.0000x reference)
//
#include <hip/hip_runtime.h>
#include <math.h>

#define KBINS 8192
#define DDIM  16384      // 2*K
#define HID   2048
#define LASTROW 16384    // the t row of W1 (row index D)

#define C1 32            // rows per mv1 block
#define NB1 512          // 16384/32 full chunks (t-row handled in h_reduce)
#define C2 32            // rows per mv2 block
#define NB2 64           // 2048/32

static constexpr float SQRT2_F = 1.4142135623730951f;

// Branch-free erf approximation (Abramowitz-Stegun 7.1.26), |err| < 1.5e-7.
__device__ __forceinline__ float fast_erff(float x) {
    float ax = fabsf(x);
    float t  = 1.0f / fmaf(0.3275911f, ax, 1.0f);
    float p  = t * (0.254829592f +
               t * (-0.284496736f +
               t * (1.421413741f +
               t * (-1.453152027f +
               t * 1.061405429f))));
    float r = 1.0f - p * __expf(-ax * ax);
    return copysignf(r, x);
}

// ---- K1: partial matvec1 over mu rows only. grid (2, 512), block 256. ----
__global__ void __launch_bounds__(256)
mv1_partial(const float* __restrict__ mu, const float* __restrict__ W1,
            float* __restrict__ part1) {
    __shared__ float a_s[C1];
    int r0 = blockIdx.y * C1;
    if (threadIdx.x < C1) a_s[threadIdx.x] = mu[r0 + threadIdx.x];
    __syncthreads();
    int c0 = (blockIdx.x * 256 + threadIdx.x) * 4;   // 0..2044
    float4 acc = {0.f, 0.f, 0.f, 0.f};
    const float* wp = W1 + (size_t)r0 * HID + c0;
#pragma unroll 8
    for (int k = 0; k < C1; ++k) {
        float a = a_s[k];
        const float4 w = *reinterpret_cast<const float4*>(wp + (size_t)k * HID);
        acc.x += a * w.x; acc.y += a * w.y; acc.z += a * w.z; acc.w += a * w.w;
    }
    *reinterpret_cast<float4*>(part1 + (size_t)blockIdx.y * HID + c0) = acc;
}

// ---- K2: h = leaky(b1 + sum_rb part1 + t * W1[lastrow]). grid 32, block 256. ----
__global__ void __launch_bounds__(256)
h_reduce(const float* __restrict__ part1, const float* __restrict__ b1,
         const float* __restrict__ W1, const float* __restrict__ t,
         float* __restrict__ h) {
    __shared__ float red[4][64];
    int lane = threadIdx.x & 63;
    int sub  = threadIdx.x >> 6;          // 0..3
    int col  = blockIdx.x * 64 + lane;
    float s = 0.f;
    for (int rb = sub; rb < NB1; rb += 4)
        s += part1[(size_t)rb * HID + col];
    red[sub][lane] = s;
    __syncthreads();
    if (threadIdx.x < 64) {
        int c = blockIdx.x * 64 + threadIdx.x;
        float v = b1[c] + t[0] * W1[(size_t)LASTROW * HID + c];
        v += red[0][threadIdx.x] + red[1][threadIdx.x]
           + red[2][threadIdx.x] + red[3][threadIdx.x];
        h[c] = (v >= 0.f) ? v : 0.01f * v;
    }
}

// ---- K3: partial matvec2. grid (16, 64), block 256. ----
__global__ void __launch_bounds__(256)
mv2_partial(const float* __restrict__ h, const float* __restrict__ W2,
            float* __restrict__ part2) {
    __shared__ float hs[C2];
    int r0 = blockIdx.y * C2;
    if (threadIdx.x < C2) hs[threadIdx.x] = h[r0 + threadIdx.x];
    __syncthreads();
    int c0 = (blockIdx.x * 256 + threadIdx.x) * 4;   // 0..16380
    float4 acc = {0.f, 0.f, 0.f, 0.f};
    const float* wp = W2 + (size_t)r0 * DDIM + c0;
#pragma unroll 8
    for (int k = 0; k < C2; ++k) {
        float a = hs[k];
        const float4 w = *reinterpret_cast<const float4*>(wp + (size_t)k * DDIM);
        acc.x += a * w.x; acc.y += a * w.y; acc.z += a * w.z; acc.w += a * w.w;
    }
    *reinterpret_cast<float4*>(part2 + (size_t)blockIdx.y * DDIM + c0) = acc;
}

// ---- K4: mu_x / sigma_x scalars. grid 32, block 256 (8192 rows). ----
__global__ void __launch_bounds__(256)
scalars(const float* __restrict__ part2, const float* __restrict__ b2,
        const float* __restrict__ mu, const float* __restrict__ t,
        const float* __restrict__ gamma,
        float* __restrict__ mu_x, float* __restrict__ sigma_x) {
    int i = blockIdx.x * 256 + threadIdx.x;
    float s0 = b2[i];
    float s1 = b2[i + KBINS];
    for (int rb = 0; rb < NB2; ++rb) {
        s0 += part2[(size_t)rb * DDIM + i];
        s1 += part2[(size_t)rb * DDIM + i + KBINS];
    }
    float g  = gamma[0];
    float pe = 1.0f / (1.0f - g);
    float pm = g - pe;
    bool use_nn = (t[0] >= 1e-10f);
    float mx = powf(mu[i], pm) * powf(s0, pe);
    float sx = powf(1.0f - g, -0.5f) * expf(0.5f * s1);
    mu_x[i]    = use_nn ? mx : 0.0f;
    sigma_x[i] = use_nn ? sx : 1.0f;
}

// ---- K5: out[i][j] = F_i(kr[j]) - F_i(kl[j]). grid 8192, block 256. ----
__global__ void __launch_bounds__(256)
cdf_row(const float* __restrict__ mu_x, const float* __restrict__ sigma_x,
        float* __restrict__ out) {
    int i   = blockIdx.x;
    int tid = threadIdx.x;
    float m   = mu_x[i];
    float inv = 1.0f / (sigma_x[i] * SQRT2_F);
    const float sc = 2.0f / 8191.0f;
    float* orow = out + (size_t)i * KBINS;
#pragma unroll
    for (int it = 0; it < 8; ++it) {
        int j0 = it * 1024 + tid * 4;
        float4 r;
        if (j0 > 4096) {
            r.x = r.y = r.z = r.w = 0.f;   // both CDFs clamp to 1 for j >= 4097
        } else {
            float F[5];
#pragma unroll
            for (int k = 0; k < 5; ++k) {
                float x = (float)(j0 - 1 + k) * sc;
                float f;
                if (x >= 1.0f)       f = 1.0f;
                else if (x <= -1.0f) f = 0.0f;
                else                 f = 0.5f * (1.0f + fast_erff((x - m) * inv));
                F[k] = f;
            }
            r.x = F[1] - F[0]; r.y = F[2] - F[1]; r.z = F[3] - F[2]; r.w = F[4] - F[3];
        }
        *reinterpret_cast<float4*>(orow + j0) = r;
    }
}

extern "C" void kernel_launch(void* const* d_in, const int* in_sizes, int n_in,
                              void* d_out, int out_size, void* d_ws, size_t ws_size,
                              hipStream_t stream) {
    const float* mu    = (const float*)d_in[0];
    const float* t     = (const float*)d_in[1];
    const float* gamma = (const float*)d_in[2];
    const float* W1    = (const float*)d_in[3];
    const float* b1    = (const float*)d_in[4];
    const float* W2    = (const float*)d_in[5];
    const float* b2    = (const float*)d_in[6];
    float* out = (float*)d_out;

    float* ws      = (float*)d_ws;
    float* part1   = ws;                             // 512*2048  = 1,048,576 floats (4 MB)
    float* h       = part1 + (size_t)NB1 * HID;      // 2048
    float* part2   = h + HID;                        // 64*16384  = 1,048,576 floats (4 MB)
    float* mu_x    = part2 + (size_t)NB2 * DDIM;     // 8192
    float* sigma_x = mu_x + KBINS;                   // 8192

    mv1_partial<<<dim3(2, NB1),  dim3(256), 0, stream>>>(mu, W1, part1);
    h_reduce   <<<dim3(32),      dim3(256), 0, stream>>>(part1, b1, W1, t, h);
    mv2_partial<<<dim3(16, NB2), dim3(256), 0, stream>>>(h, W2, part2);
    scalars    <<<dim3(32),      dim3(256), 0, stream>>>(part2, b2, mu, t, gamma, mu_x, sigma_x);
    cdf_row    <<<dim3(KBINS),   dim3(256), 0, stream>>>(mu_x, sigma_x, out);
}

// Round 4
// 147.773 us; speedup vs baseline: 1.1246x; 1.1246x over previous
//
#include <hip/hip_runtime.h>
#include <math.h>

#define KBINS 8192
#define DDIM  16384      // 2*K
#define HID   2048
#define LASTROW 16384    // the t row of W1 (row index D)

#define C1 32            // rows per mv1 block
#define NB1 512          // 16384/32 full chunks (t-row handled in h_reduce)
#define C2 32            // rows per mv2 block
#define NB2 64           // 2048/32

static constexpr float SQRT2_F  = 1.4142135623730951f;
static constexpr float INVSQ2PI = 0.3989422804014327f;   // 1/sqrt(2*pi)

// Branch-free erf approximation (Abramowitz-Stegun 7.1.26), |err| < 1.5e-7.
// Only used for the single clamped column j==4096 (one eval per row).
__device__ __forceinline__ float fast_erff(float x) {
    float ax = fabsf(x);
    float t  = 1.0f / fmaf(0.3275911f, ax, 1.0f);
    float p  = t * (0.254829592f +
               t * (-0.284496736f +
               t * (1.421413741f +
               t * (-1.453152027f +
               t * 1.061405429f))));
    float r = 1.0f - p * __expf(-ax * ax);
    return copysignf(r, x);
}

// ---- K1: partial matvec1 over mu rows only. grid (2, 512), block 256. ----
__global__ void __launch_bounds__(256)
mv1_partial(const float* __restrict__ mu, const float* __restrict__ W1,
            float* __restrict__ part1) {
    __shared__ float a_s[C1];
    int r0 = blockIdx.y * C1;
    if (threadIdx.x < C1) a_s[threadIdx.x] = mu[r0 + threadIdx.x];
    __syncthreads();
    int c0 = (blockIdx.x * 256 + threadIdx.x) * 4;   // 0..2044
    float4 acc0 = {0.f, 0.f, 0.f, 0.f};
    float4 acc1 = {0.f, 0.f, 0.f, 0.f};
    const float* wp = W1 + (size_t)r0 * HID + c0;
#pragma unroll
    for (int k = 0; k < C1; k += 2) {
        float a0 = a_s[k];
        float a1 = a_s[k + 1];
        const float4 w0 = *reinterpret_cast<const float4*>(wp + (size_t)k * HID);
        const float4 w1 = *reinterpret_cast<const float4*>(wp + (size_t)(k + 1) * HID);
        acc0.x += a0 * w0.x; acc0.y += a0 * w0.y; acc0.z += a0 * w0.z; acc0.w += a0 * w0.w;
        acc1.x += a1 * w1.x; acc1.y += a1 * w1.y; acc1.z += a1 * w1.z; acc1.w += a1 * w1.w;
    }
    float4 acc = {acc0.x + acc1.x, acc0.y + acc1.y, acc0.z + acc1.z, acc0.w + acc1.w};
    *reinterpret_cast<float4*>(part1 + (size_t)blockIdx.y * HID + c0) = acc;
}

// ---- K2: h = leaky(b1 + sum_rb part1 + t * W1[lastrow]). grid 32, block 256. ----
__global__ void __launch_bounds__(256)
h_reduce(const float* __restrict__ part1, const float* __restrict__ b1,
         const float* __restrict__ W1, const float* __restrict__ t,
         float* __restrict__ h) {
    __shared__ float red[4][64];
    int lane = threadIdx.x & 63;
    int sub  = threadIdx.x >> 6;          // 0..3
    int col  = blockIdx.x * 64 + lane;
    float s = 0.f;
#pragma unroll 8
    for (int rb = sub; rb < NB1; rb += 4)
        s += part1[(size_t)rb * HID + col];
    red[sub][lane] = s;
    __syncthreads();
    if (threadIdx.x < 64) {
        int c = blockIdx.x * 64 + threadIdx.x;
        float v = b1[c] + t[0] * W1[(size_t)LASTROW * HID + c];
        v += red[0][threadIdx.x] + red[1][threadIdx.x]
           + red[2][threadIdx.x] + red[3][threadIdx.x];
        h[c] = (v >= 0.f) ? v : 0.01f * v;
    }
}

// ---- K3: partial matvec2. grid (16, 64), block 256. ----
__global__ void __launch_bounds__(256)
mv2_partial(const float* __restrict__ h, const float* __restrict__ W2,
            float* __restrict__ part2) {
    __shared__ float hs[C2];
    int r0 = blockIdx.y * C2;
    if (threadIdx.x < C2) hs[threadIdx.x] = h[r0 + threadIdx.x];
    __syncthreads();
    int c0 = (blockIdx.x * 256 + threadIdx.x) * 4;   // 0..16380
    float4 acc0 = {0.f, 0.f, 0.f, 0.f};
    float4 acc1 = {0.f, 0.f, 0.f, 0.f};
    const float* wp = W2 + (size_t)r0 * DDIM + c0;
#pragma unroll
    for (int k = 0; k < C2; k += 2) {
        float a0 = hs[k];
        float a1 = hs[k + 1];
        const float4 w0 = *reinterpret_cast<const float4*>(wp + (size_t)k * DDIM);
        const float4 w1 = *reinterpret_cast<const float4*>(wp + (size_t)(k + 1) * DDIM);
        acc0.x += a0 * w0.x; acc0.y += a0 * w0.y; acc0.z += a0 * w0.z; acc0.w += a0 * w0.w;
        acc1.x += a1 * w1.x; acc1.y += a1 * w1.y; acc1.z += a1 * w1.z; acc1.w += a1 * w1.w;
    }
    float4 acc = {acc0.x + acc1.x, acc0.y + acc1.y, acc0.z + acc1.z, acc0.w + acc1.w};
    *reinterpret_cast<float4*>(part2 + (size_t)blockIdx.y * DDIM + c0) = acc;
}

// ---- K4: mu_x / sigma_x scalars. grid 32, block 256 (8192 rows). ----
__global__ void __launch_bounds__(256)
scalars(const float* __restrict__ part2, const float* __restrict__ b2,
        const float* __restrict__ mu, const float* __restrict__ t,
        const float* __restrict__ gamma,
        float* __restrict__ mu_x, float* __restrict__ sigma_x) {
    int i = blockIdx.x * 256 + threadIdx.x;
    float s0 = b2[i];
    float s1 = b2[i + KBINS];
#pragma unroll 8
    for (int rb = 0; rb < NB2; ++rb) {
        s0 += part2[(size_t)rb * DDIM + i];
        s1 += part2[(size_t)rb * DDIM + i + KBINS];
    }
    float g  = gamma[0];
    float pe = 1.0f / (1.0f - g);
    float pm = g - pe;
    bool use_nn = (t[0] >= 1e-10f);
    float mx = powf(mu[i], pm) * powf(s0, pe);
    float sx = powf(1.0f - g, -0.5f) * expf(0.5f * s1);
    mu_x[i]    = use_nn ? mx : 0.0f;
    sigma_x[i] = use_nn ? sx : 1.0f;
}

// ---- K5: out[i][j] = F_i(kr[j]) - F_i(kl[j]) via midpoint rule. grid 8192, block 256. ----
// For 0 <= j <= 4095 (no clamps active): F(kr)-F(kl) = Delta * pdf(mid) + O(Delta^3*pdf'')
// with Delta = 2/8191, mid = (2j-1)/8191. sigma_x ~ 1.4 => error ~1e-13, far below tol.
// j == 4096: kr clamps to 1 -> out = 1 - F(kl) = 0.5*(1 - erf(z)). j >= 4097: exactly 0.
__global__ void __launch_bounds__(256)
cdf_row(const float* __restrict__ mu_x, const float* __restrict__ sigma_x,
        float* __restrict__ out) {
    int i   = blockIdx.x;
    int tid = threadIdx.x;
    float m    = mu_x[i];
    float invs = 1.0f / sigma_x[i];
    const float sc = 2.0f / 8191.0f;
    float A    = sc * invs;                          // du/dj
    float B    = (-1.0f / 8191.0f - m) * invs;       // u at j=0
    float coef = INVSQ2PI * A;                       // Delta * pdf scale
    float* orow = out + (size_t)i * KBINS;
#pragma unroll
    for (int it = 0; it < 8; ++it) {
        int j0 = it * 1024 + tid * 4;
        float4 r;
        if (j0 < 4096) {
            float u0 = fmaf((float)(j0 + 0), A, B);
            float u1 = fmaf((float)(j0 + 1), A, B);
            float u2 = fmaf((float)(j0 + 2), A, B);
            float u3 = fmaf((float)(j0 + 3), A, B);
            r.x = coef * __expf(-0.5f * u0 * u0);
            r.y = coef * __expf(-0.5f * u1 * u1);
            r.z = coef * __expf(-0.5f * u2 * u2);
            r.w = coef * __expf(-0.5f * u3 * u3);
        } else if (j0 == 4096) {
            float z = (8190.0f / 8191.0f - m) * invs * (1.0f / SQRT2_F);
            r.x = 0.5f * (1.0f - fast_erff(z));
            r.y = r.z = r.w = 0.f;
        } else {
            r.x = r.y = r.z = r.w = 0.f;
        }
        *reinterpret_cast<float4*>(orow + j0) = r;
    }
}

extern "C" void kernel_launch(void* const* d_in, const int* in_sizes, int n_in,
                              void* d_out, int out_size, void* d_ws, size_t ws_size,
                              hipStream_t stream) {
    const float* mu    = (const float*)d_in[0];
    const float* t     = (const float*)d_in[1];
    const float* gamma = (const float*)d_in[2];
    const float* W1    = (const float*)d_in[3];
    const float* b1    = (const float*)d_in[4];
    const float* W2    = (const float*)d_in[5];
    const float* b2    = (const float*)d_in[6];
    float* out = (float*)d_out;

    float* ws      = (float*)d_ws;
    float* part1   = ws;                             // 512*2048  = 1,048,576 floats (4 MB)
    float* h       = part1 + (size_t)NB1 * HID;      // 2048
    float* part2   = h + HID;                        // 64*16384  = 1,048,576 floats (4 MB)
    float* mu_x    = part2 + (size_t)NB2 * DDIM;     // 8192
    float* sigma_x = mu_x + KBINS;                   // 8192

    mv1_partial<<<dim3(2, NB1),  dim3(256), 0, stream>>>(mu, W1, part1);
    h_reduce   <<<dim3(32),      dim3(256), 0, stream>>>(part1, b1, W1, t, h);
    mv2_partial<<<dim3(16, NB2), dim3(256), 0, stream>>>(h, W2, part2);
    scalars    <<<dim3(32),      dim3(256), 0, stream>>>(part2, b2, mu, t, gamma, mu_x, sigma_x);
    cdf_row    <<<dim3(KBINS),   dim3(256), 0, stream>>>(mu_x, sigma_x, out);
}